// Round 13
// baseline (29.677 us; speedup 1.0000x reference)
//
#include <hip/hip_runtime.h>

// ROUND 13 = ROUND 12 + intra-kernel ABLATION of triplet (template<MODE>).
// MODE 0 = real (byte-identical math to R12). MODE 1 = drow+compact only.
// MODE 2 = compact+loop only (synthetic drow, no dotp reads). Modes 1/2 write
// scratch buffers that nothing reads. Decision table in journal.

#define EPSF 1e-8f
#define MARGINF 0.5f
#define BN 512
#define DD 768
#define BT 64
#define SPLITK 8
#define KC (DD / SPLITK)  // 96
#define LPAD 104
#define NORMBLK 128

typedef __attribute__((ext_vector_type(8))) short bf16x8;
typedef __attribute__((ext_vector_type(4))) float f32x4;

__device__ __forceinline__ short f2bf(float f) {
    unsigned int u = __float_as_uint(f);
    return (short)((u + 0x7FFFu + ((u >> 16) & 1u)) >> 16);  // RNE
}

__device__ __forceinline__ bf16x8 pack8(const float4& a, const float4& b) {
    bf16x8 r;
    r[0] = f2bf(a.x); r[1] = f2bf(a.y); r[2] = f2bf(a.z); r[3] = f2bf(a.w);
    r[4] = f2bf(b.x); r[5] = f2bf(b.y); r[6] = f2bf(b.z); r[7] = f2bf(b.w);
    return r;
}

// ---------------- Node 1: MFMA gram partials + norms (byte-identical to R12) ----------------
__global__ __launch_bounds__(256) void prep_kernel(const float* __restrict__ x,
                                                   float* __restrict__ invn,
                                                   float* __restrict__ dotp) {
    int b = blockIdx.x;
    int t = threadIdx.x;
    int wv = t >> 6, lane = t & 63;

    if (b >= BN) {
        int row = (b - BN) * 4 + wv;
        float s = 0.f;
#pragma unroll
        for (int c = 0; c < 3; ++c) {
            float4 v = *(const float4*)&x[row * DD + (lane + c * 64) * 4];
            s += v.x * v.x + v.y * v.y + v.z * v.z + v.w * v.w;
        }
        for (int off = 32; off; off >>= 1) s += __shfl_down(s, off, 64);
        if (lane == 0) invn[row] = 1.0f / fmaxf(sqrtf(s), EPSF);
        return;
    }

    __shared__ __align__(16) short As[BT][LPAD];
    __shared__ __align__(16) short Bs[BT][LPAD];
    int bz = b >> 6, bi = (b >> 3) & 7, bj = b & 7;
    int i0 = bi * BT, j0 = bj * BT, kbase = bz * KC;

    {
        int row = t >> 2, fq = t & 3;
        const float* ap = &x[(i0 + row) * DD + kbase + fq * 8];
        const float* bp = &x[(j0 + row) * DD + kbase + fq * 8];
#pragma unroll
        for (int cc = 0; cc < 3; ++cc) {
            float4 a0 = *(const float4*)(ap + cc * 32);
            float4 a1 = *(const float4*)(ap + cc * 32 + 4);
            float4 b0 = *(const float4*)(bp + cc * 32);
            float4 b1 = *(const float4*)(bp + cc * 32 + 4);
            *(bf16x8*)&As[row][fq * 8 + cc * 32] = pack8(a0, a1);
            *(bf16x8*)&Bs[row][fq * 8 + cc * 32] = pack8(b0, b1);
        }
    }
    __syncthreads();

    int r16 = lane & 15;
    int kb8 = (lane >> 4) * 8;

    f32x4 accf[4];
#pragma unroll
    for (int c = 0; c < 4; ++c) accf[c] = (f32x4){0.f, 0.f, 0.f, 0.f};

#pragma unroll
    for (int s = 0; s < 3; ++s) {
        bf16x8 af = *(const bf16x8*)&As[wv * 16 + r16][kb8 + s * 32];
#pragma unroll
        for (int c = 0; c < 4; ++c) {
            bf16x8 bf_ = *(const bf16x8*)&Bs[c * 16 + r16][kb8 + s * 32];
            accf[c] = __builtin_amdgcn_mfma_f32_16x16x32_bf16(af, bf_, accf[c], 0, 0, 0);
        }
    }

    float* o = dotp + (size_t)bz * BN * BN;
    int crow = i0 + wv * 16 + (lane >> 4) * 4;
#pragma unroll
    for (int c = 0; c < 4; ++c) {
        int ccol = j0 + c * 16 + r16;
#pragma unroll
        for (int r = 0; r < 4; ++r)
            o[(crow + r) * BN + ccol] = accf[c][r];
    }
}

// ---------------- Node 2: triplet (template ablation) ----------------
template <int MODE>
__global__ __launch_bounds__(256) void triplet_kernel(const float* __restrict__ dotp,
                                                      const float* __restrict__ invn,
                                                      const int* __restrict__ labels,
                                                      float* __restrict__ psum,
                                                      unsigned int* __restrict__ pcnt) {
    int i = blockIdx.x;
    int t = threadIdx.x;
    int w = t >> 6, lane = t & 63;
    __shared__ float drow[BN];
    __shared__ int lab[BN];
    __shared__ __align__(16) float dpos[528];
    __shared__ int wcnt[8];
    __shared__ int woff[9];
    __shared__ float redf[4];
    __shared__ unsigned int redc[4];

    lab[t] = labels[t];
    lab[t + 256] = labels[t + 256];
    float inv_i = invn[i];
#pragma unroll
    for (int e0 = 0; e0 < BN; e0 += 256) {
        int e = e0 + t;
        if constexpr (MODE == 2) {
            // synthetic drow: NO dotp reads (ablates the drow-load phase)
            drow[e] = 1.0f - (float)((e * 37) & 255) * 0.001f * inv_i;
        } else {
            float s = 0.f;
#pragma unroll
            for (int z = 0; z < SPLITK; ++z) s += dotp[(size_t)z * BN * BN + i * BN + e];
            drow[e] = 1.0f - s * inv_i * invn[e];
        }
    }
    __syncthreads();

    int li = lab[i];
    bool p0 = (lab[t] == li) && (t != i);
    bool p1 = (lab[t + 256] == li) && ((t + 256) != i);
    unsigned long long m0 = __ballot(p0);
    unsigned long long m1 = __ballot(p1);
    if (lane == 0) { wcnt[w] = __popcll(m0); wcnt[4 + w] = __popcll(m1); }
    __syncthreads();
    if (t == 0) {
        int s = 0;
#pragma unroll
        for (int q = 0; q < 8; ++q) { woff[q] = s; s += wcnt[q]; }
        woff[8] = s;
    }
    __syncthreads();
    unsigned long long lmask = (1ull << lane) - 1ull;
    if (p0) dpos[woff[w] + __popcll(m0 & lmask)] = drow[t] + MARGINF;
    if (p1) dpos[woff[4 + w] + __popcll(m1 & lmask)] = drow[t + 256] + MARGINF;
    int npos = woff[8];
    int npad = (npos + 15) & ~15;
    if (t < npad - npos) dpos[npos + t] = -1e30f;
    __syncthreads();

    float dk0 = (lab[t] != li) ? drow[t] : 1e30f;
    float dk1 = (lab[t + 256] != li) ? drow[t + 256] : 1e30f;

    if constexpr (MODE == 1) {
        // ablate the main loop; keep drow loads + compact live (rule 17)
        float v = dpos[lane] + dk0 + dk1;
        asm volatile("" :: "v"(v));
        if (t == 0) { psum[i] = dpos[0] + dpos[npad - 1]; pcnt[i] = (unsigned)npos; }
        return;
    }

    float sum = 0.f;
    unsigned int cnt = 0;
    for (int n = 0; n < npad; n += 16) {
        float4 q[4];
#pragma unroll
        for (int v = 0; v < 4; ++v) q[v] = *(const float4*)&dpos[n + v * 4];
#pragma unroll
        for (int v = 0; v < 4; ++v) {
            float bv[4] = {q[v].x, q[v].y, q[v].z, q[v].w};
#pragma unroll
            for (int u = 0; u < 4; ++u) {
                float v0 = bv[u] - dk0;
                float v1 = bv[u] - dk1;
                sum += fmaxf(v0, 0.f);
                if (v0 > EPSF) cnt++;
                sum += fmaxf(v1, 0.f);
                if (v1 > EPSF) cnt++;
            }
        }
    }
    for (int off = 32; off; off >>= 1) {
        sum += __shfl_down(sum, off, 64);
        cnt += __shfl_down(cnt, off, 64);
    }
    if (lane == 0) { redf[w] = sum; redc[w] = cnt; }
    __syncthreads();
    if (t == 0) {
        psum[i] = redf[0] + redf[1] + redf[2] + redf[3];
        pcnt[i] = redc[0] + redc[1] + redc[2] + redc[3];
    }
}

// ---------------- Node 3: final reduce ----------------
__global__ __launch_bounds__(256) void reduce_kernel(const float* __restrict__ psum,
                                                     const unsigned int* __restrict__ pcnt,
                                                     float* __restrict__ out) {
    int t = threadIdx.x;
    double s = (double)psum[t] + (double)psum[t + 256];
    double c = (double)pcnt[t] + (double)pcnt[t + 256];
    for (int off = 32; off; off >>= 1) {
        s += __shfl_down(s, off, 64);
        c += __shfl_down(c, off, 64);
    }
    __shared__ double sred[4], cred[4];
    if ((t & 63) == 0) { sred[t >> 6] = s; cred[t >> 6] = c; }
    __syncthreads();
    if (t == 0) {
        double stot = sred[0] + sred[1] + sred[2] + sred[3];
        double ctot = cred[0] + cred[1] + cred[2] + cred[3];
        out[0] = (float)(stot / (ctot + 1e-8));
    }
}

extern "C" void kernel_launch(void* const* d_in, const int* in_sizes, int n_in,
                              void* d_out, int out_size, void* d_ws, size_t ws_size,
                              hipStream_t stream) {
    const float* x = (const float*)d_in[0];
    const int* labels = (const int*)d_in[1];
    float* out = (float*)d_out;

    char* ws = (char*)d_ws;
    float* invn = (float*)(ws + 256);                 // 2 KB
    float* psum = (float*)(ws + 4096);                // 2 KB  (real)
    unsigned int* pcnt = (unsigned int*)(ws + 8192);  // 2 KB  (real)
    float* dsum = (float*)(ws + 12288);               // 2 KB  (ablation scratch)
    unsigned int* dcnt = (unsigned int*)(ws + 14336); // 2 KB  (ablation scratch)
    float* dotp = (float*)(ws + 16384);               // 8 MB

    prep_kernel<<<BN + NORMBLK, 256, 0, stream>>>(x, invn, dotp);
    triplet_kernel<0><<<BN, 256, 0, stream>>>(dotp, invn, labels, psum, pcnt);  // real
    triplet_kernel<1><<<BN, 256, 0, stream>>>(dotp, invn, labels, dsum, dcnt);  // D+C probe
    triplet_kernel<1><<<BN, 256, 0, stream>>>(dotp, invn, labels, dsum, dcnt);  // D+C probe
    triplet_kernel<2><<<BN, 256, 0, stream>>>(dotp, invn, labels, dsum, dcnt);  // C+L probe
    reduce_kernel<<<1, 256, 0, stream>>>(psum, pcnt, out);
}

// Round 14
// 19.655 us; speedup vs baseline: 1.5098x; 1.5098x over previous
//
#include <hip/hip_runtime.h>

#define EPSF 1e-8f
#define MARGINF 0.5f
#define BN 512
#define DD 768
#define BT 64
#define GBLK 64    // gram blocks: one full-K 64x64 tile each (no split-K -> no 8MB RAW surface)
#define NBLK 32    // norm blocks: 16 rows each (1024-thread blocks, one row/wave)
#define CHK 128    // K-chunk staged per barrier pair
#define NCHK 6     // 768/128
#define LP 136     // LDS row stride (shorts): 272B, 68 dwords % 32 = 4 -> max 2-way (free)

typedef __attribute__((ext_vector_type(8))) short bf16x8;
typedef __attribute__((ext_vector_type(4))) float f32x4;

__device__ __forceinline__ short f2bf(float f) {
    unsigned int u = __float_as_uint(f);
    return (short)((u + 0x7FFFu + ((u >> 16) & 1u)) >> 16);  // RNE
}

__device__ __forceinline__ bf16x8 pack8(const float4& a, const float4& b) {
    bf16x8 r;
    r[0] = f2bf(a.x); r[1] = f2bf(a.y); r[2] = f2bf(a.z); r[3] = f2bf(a.w);
    r[4] = f2bf(b.x); r[5] = f2bf(b.y); r[6] = f2bf(b.z); r[7] = f2bf(b.w);
    return r;
}

// ---------------- Node 1: full-K MFMA gram (blocks 0..63) + norms (64..95) ----------------
// 1024 threads = 16 waves. Gram block (bi,bj): wave w -> frag (w>>2, w&3) of the
// 64x64 tile; K=768 in 6 LDS chunks of 128. dist gets the FINAL raw dot (f32, 1MB).
__global__ __launch_bounds__(1024) void prep_kernel(const float* __restrict__ x,
                                                    float* __restrict__ invn,
                                                    float* __restrict__ dist) {
    int b = blockIdx.x;
    int t = threadIdx.x;
    int wv = t >> 6, lane = t & 63;

    if (b >= GBLK) {
        // ----- norm task: one row per wave -----
        int row = (b - GBLK) * 16 + wv;
        float s = 0.f;
#pragma unroll
        for (int c = 0; c < 3; ++c) {
            float4 v = *(const float4*)&x[row * DD + (lane + c * 64) * 4];
            s += v.x * v.x + v.y * v.y + v.z * v.z + v.w * v.w;
        }
        for (int off = 32; off; off >>= 1) s += __shfl_down(s, off, 64);
        if (lane == 0) invn[row] = 1.0f / fmaxf(sqrtf(s), EPSF);
        return;
    }

    __shared__ __align__(16) short As[BT][LP];   // 17.4 KB
    __shared__ __align__(16) short Bs[BT][LP];   // 34.8 KB total
    int bi = b >> 3, bj = b & 7;
    int i0 = bi * BT, j0 = bj * BT;

    int wr = wv >> 2, wc = wv & 3;        // wave's 16x16 fragment position
    int r16 = lane & 15, kb8 = (lane >> 4) * 8;
    int srow = t >> 4, sf = (t & 15) * 8; // staging: 16 threads/row x 8 floats

    const float* arow = &x[(i0 + srow) * DD + sf];
    const float* brow = &x[(j0 + srow) * DD + sf];

    f32x4 acc = (f32x4){0.f, 0.f, 0.f, 0.f};
    for (int c = 0; c < NCHK; ++c) {
        int kb = c * CHK;
        float4 a0 = *(const float4*)(arow + kb);
        float4 a1 = *(const float4*)(arow + kb + 4);
        float4 b0 = *(const float4*)(brow + kb);
        float4 b1 = *(const float4*)(brow + kb + 4);
        __syncthreads();   // previous chunk's fragment reads done
        *(bf16x8*)&As[srow][sf] = pack8(a0, a1);
        *(bf16x8*)&Bs[srow][sf] = pack8(b0, b1);
        __syncthreads();
#pragma unroll
        for (int s = 0; s < 4; ++s) {
            bf16x8 af = *(const bf16x8*)&As[wr * 16 + r16][kb8 + s * 32];
            bf16x8 bf_ = *(const bf16x8*)&Bs[wc * 16 + r16][kb8 + s * 32];
            acc = __builtin_amdgcn_mfma_f32_16x16x32_bf16(af, bf_, acc, 0, 0, 0);
        }
    }

    // C/D layout: col = lane&15, row = (lane>>4)*4 + reg   [verified R6-R13]
    int crow = i0 + wr * 16 + (lane >> 4) * 4;
    int ccol = j0 + wc * 16 + r16;
#pragma unroll
    for (int r = 0; r < 4; ++r)
        dist[(crow + r) * BN + ccol] = acc[r];
}

// ---------------- Node 2: triplet — single dist read, compact list, b128 branchless loop ----------------
__global__ __launch_bounds__(256) void triplet_kernel(const float* __restrict__ dist,
                                                      const float* __restrict__ invn,
                                                      const int* __restrict__ labels,
                                                      float* __restrict__ psum,
                                                      unsigned int* __restrict__ pcnt) {
    int i = blockIdx.x;
    int t = threadIdx.x;
    int w = t >> 6, lane = t & 63;
    __shared__ float drow[BN];
    __shared__ int lab[BN];
    __shared__ __align__(16) float dpos[528];
    __shared__ int wcnt[8];
    __shared__ int woff[9];
    __shared__ float redf[4];
    __shared__ unsigned int redc[4];

    lab[t] = labels[t];
    lab[t + 256] = labels[t + 256];
    float inv_i = invn[i];
    {
        float2 iv = *(const float2*)&invn[2 * t];
        float2 p = *(const float2*)&dist[i * BN + 2 * t];
        drow[2 * t]     = 1.0f - p.x * inv_i * iv.x;
        drow[2 * t + 1] = 1.0f - p.y * inv_i * iv.y;
    }
    __syncthreads();

    int li = lab[i];
    bool p0 = (lab[t] == li) && (t != i);
    bool p1 = (lab[t + 256] == li) && ((t + 256) != i);
    unsigned long long m0 = __ballot(p0);
    unsigned long long m1 = __ballot(p1);
    if (lane == 0) { wcnt[w] = __popcll(m0); wcnt[4 + w] = __popcll(m1); }
    __syncthreads();
    if (t == 0) {
        int s = 0;
#pragma unroll
        for (int q = 0; q < 8; ++q) { woff[q] = s; s += wcnt[q]; }
        woff[8] = s;
    }
    __syncthreads();
    unsigned long long lmask = (1ull << lane) - 1ull;
    if (p0) dpos[woff[w] + __popcll(m0 & lmask)] = drow[t] + MARGINF;
    if (p1) dpos[woff[4 + w] + __popcll(m1 & lmask)] = drow[t + 256] + MARGINF;
    int npos = woff[8];
    int npad = (npos + 15) & ~15;
    if (t < npad - npos) dpos[npos + t] = -1e30f;   // pad: contributes exactly 0
    __syncthreads();

    float dk0 = (lab[t] != li) ? drow[t] : 1e30f;
    float dk1 = (lab[t + 256] != li) ? drow[t + 256] : 1e30f;
    float sum = 0.f;
    unsigned int cnt = 0;
    for (int n = 0; n < npad; n += 16) {
        float4 q[4];
#pragma unroll
        for (int v = 0; v < 4; ++v) q[v] = *(const float4*)&dpos[n + v * 4];
#pragma unroll
        for (int v = 0; v < 4; ++v) {
            float bv[4] = {q[v].x, q[v].y, q[v].z, q[v].w};
#pragma unroll
            for (int u = 0; u < 4; ++u) {
                float v0 = bv[u] - dk0;
                float v1 = bv[u] - dk1;
                sum += fmaxf(v0, 0.f);
                if (v0 > EPSF) cnt++;
                sum += fmaxf(v1, 0.f);
                if (v1 > EPSF) cnt++;
            }
        }
    }
    for (int off = 32; off; off >>= 1) {
        sum += __shfl_down(sum, off, 64);
        cnt += __shfl_down(cnt, off, 64);
    }
    if (lane == 0) { redf[w] = sum; redc[w] = cnt; }
    __syncthreads();
    if (t == 0) {
        psum[i] = redf[0] + redf[1] + redf[2] + redf[3];
        pcnt[i] = redc[0] + redc[1] + redc[2] + redc[3];
    }
}

// ---------------- Node 3: final reduce (1 block, deterministic) ----------------
__global__ __launch_bounds__(256) void reduce_kernel(const float* __restrict__ psum,
                                                     const unsigned int* __restrict__ pcnt,
                                                     float* __restrict__ out) {
    int t = threadIdx.x;
    double s = (double)psum[t] + (double)psum[t + 256];
    double c = (double)pcnt[t] + (double)pcnt[t + 256];
    for (int off = 32; off; off >>= 1) {
        s += __shfl_down(s, off, 64);
        c += __shfl_down(c, off, 64);
    }
    __shared__ double sred[4], cred[4];
    if ((t & 63) == 0) { sred[t >> 6] = s; cred[t >> 6] = c; }
    __syncthreads();
    if (t == 0) {
        double stot = sred[0] + sred[1] + sred[2] + sred[3];
        double ctot = cred[0] + cred[1] + cred[2] + cred[3];
        out[0] = (float)(stot / (ctot + 1e-8));
    }
}

extern "C" void kernel_launch(void* const* d_in, const int* in_sizes, int n_in,
                              void* d_out, int out_size, void* d_ws, size_t ws_size,
                              hipStream_t stream) {
    const float* x = (const float*)d_in[0];
    const int* labels = (const int*)d_in[1];
    float* out = (float*)d_out;

    char* ws = (char*)d_ws;
    float* invn = (float*)(ws + 256);               // 2 KB
    float* psum = (float*)(ws + 4096);              // 2 KB
    unsigned int* pcnt = (unsigned int*)(ws + 8192);// 2 KB
    float* dist = (float*)(ws + 16384);             // 1 MB (raw dots, final)

    prep_kernel<<<GBLK + NBLK, 1024, 0, stream>>>(x, invn, dist);
    triplet_kernel<<<BN, 256, 0, stream>>>(dist, invn, labels, psum, pcnt);
    reduce_kernel<<<1, 256, 0, stream>>>(psum, pcnt, out);
}